// Round 15
// baseline (813.572 us; speedup 1.0000x reference)
//
#include <hip/hip_runtime.h>

// ---------------- problem constants ----------------
#define T_LEN 2048
#define B_SZ  4
#define D_DIM 2048
#define H_DIM 8192
#define BT    (B_SZ * T_LEN)

typedef float f32x4 __attribute__((ext_vector_type(4)));
typedef int   i32x4v __attribute__((ext_vector_type(4)));
typedef int   i32x16v __attribute__((ext_vector_type(16)));
typedef unsigned short ushort8 __attribute__((ext_vector_type(8)));

__device__ __forceinline__ float bf2f(unsigned short u) {
    unsigned int i = ((unsigned int)u) << 16;
    return __builtin_bit_cast(float, i);
}
__device__ __forceinline__ unsigned short f2bf(float f) {
    unsigned int i = __builtin_bit_cast(unsigned int, f);
    i += 0x7fffu + ((i >> 16) & 1u);   // RNE
    return (unsigned short)(i >> 16);
}

// ---------------- block reduction (blockDim == 256) ----------------
__device__ __forceinline__ float block_sum(float v, float* red) {
    #pragma unroll
    for (int o = 32; o > 0; o >>= 1) v += __shfl_down(v, o, 64);
    const int lane = threadIdx.x & 63, w = threadIdx.x >> 6;
    if (lane == 0) red[w] = v;
    __syncthreads();
    float r = red[0] + red[1] + red[2] + red[3];
    __syncthreads();
    return r;
}

// ---------------- fused weight-prep ----------------
__global__ void wabs_all(const float* __restrict__ wk, const float* __restrict__ wr,
                         const float* __restrict__ wv, float* __restrict__ part) {
    __shared__ float red[16];
    const int m = blockIdx.x >> 10;
    const int blk = blockIdx.x & 1023;
    const float* w = (m == 0) ? wk : (m == 1) ? wr : wv;
    const int n = (m == 1) ? D_DIM * D_DIM : H_DIM * D_DIM;
    float s = 0.f;
    int i = (blk * 256 + threadIdx.x) * 8;
    const int stride = 1024 * 256 * 8;
    for (; i < n; i += stride) {
        f32x4 a = *(const f32x4*)(w + i);
        f32x4 b = *(const f32x4*)(w + i + 4);
        #pragma unroll
        for (int j = 0; j < 4; j++) s += fabsf(a[j]) + fabsf(b[j]);
    }
    float tot = block_sum(s, red);
    if (threadIdx.x == 0) part[blockIdx.x] = tot;
}

__global__ void wfinal_all(const float* __restrict__ part, float* __restrict__ wsc) {
    __shared__ float red[16];
    const int m = blockIdx.x;
    const int n = (m == 1) ? D_DIM * D_DIM : H_DIM * D_DIM;
    float s = 0.f;
    for (int i = threadIdx.x; i < 1024; i += 256) s += part[m * 1024 + i];
    float tot = block_sum(s, red);
    if (threadIdx.x == 0) wsc[m] = fmaxf(tot / (float)n, 1e-8f);
}

__global__ void wquant_all(const float* __restrict__ wk, const float* __restrict__ wr,
                           const float* __restrict__ wv,
                           signed char* __restrict__ qk, signed char* __restrict__ qr,
                           signed char* __restrict__ qv,
                           const float* __restrict__ wsc) {
    const int b = blockIdx.x;
    int m, blk, nblk;
    if (b < 2048)      { m = 0; blk = b;        nblk = 2048; }
    else if (b < 3072) { m = 1; blk = b - 2048; nblk = 1024; }
    else               { m = 2; blk = b - 3072; nblk = 2048; }
    const float* w = (m == 0) ? wk : (m == 1) ? wr : wv;
    signed char* q = (m == 0) ? qk : (m == 1) ? qr : qv;
    const int n = (m == 1) ? D_DIM * D_DIM : H_DIM * D_DIM;
    const float s = wsc[m];
    int i = (blk * 256 + threadIdx.x) * 16;
    const int stride = nblk * 256 * 16;
    for (; i < n; i += stride) {
        union { signed char c[16]; i32x4v v; } pk;
        #pragma unroll
        for (int h = 0; h < 4; h++) {
            f32x4 a = *(const f32x4*)(w + i + h * 4);
            #pragma unroll
            for (int j = 0; j < 4; j++)
                pk.c[h * 4 + j] =
                    (signed char)(int)rintf(fminf(fmaxf(a[j] / s, -1.f), 1.f));
        }
        *(i32x4v*)(q + i) = pk.v;
    }
}

// ---------------- LN + act quant, PACKED-fragment output ----------------
// Packed layout: byte of (row r, k) at ((r>>5)*(K/16) + k/16)*512 + (r&31)*16 + (k%16).
__device__ __forceinline__ void ln_quant8(const float* xm_in,
                                          const float* __restrict__ g,
                                          const float* __restrict__ b,
                                          signed char* qbase, int row,
                                          float* srow, float* red) {
    const int base = threadIdx.x * 8;
    float xm[8];
    float s = 0.f;
    #pragma unroll
    for (int j = 0; j < 8; j++) { xm[j] = xm_in[j]; s += xm[j]; }
    const float mean = block_sum(s, red) * (1.f / D_DIM);
    float s2 = 0.f;
    #pragma unroll
    for (int j = 0; j < 8; j++) { float d = xm[j] - mean; s2 += d * d; }
    const float var  = block_sum(s2, red) * (1.f / D_DIM);
    const float rstd = 1.f / sqrtf(var + 1e-5f);
    f32x4 ga = *(const f32x4*)(g + base), gb = *(const f32x4*)(g + base + 4);
    f32x4 ba = *(const f32x4*)(b + base), bb2 = *(const f32x4*)(b + base + 4);
    float gg[8] = {ga[0],ga[1],ga[2],ga[3],gb[0],gb[1],gb[2],gb[3]};
    float bb[8] = {ba[0],ba[1],ba[2],ba[3],bb2[0],bb2[1],bb2[2],bb2[3]};
    float sa = 0.f;
    #pragma unroll
    for (int j = 0; j < 8; j++) {
        xm[j] = (xm[j] - mean) * rstd * gg[j] + bb[j];
        sa += fabsf(xm[j]);
    }
    const float amean = block_sum(sa, red) * (1.f / D_DIM);
    const float scale = fmaxf(amean, 1e-8f) * 2.5f / 127.0f;
    union { signed char c[8]; int2 v; } pk;
    #pragma unroll
    for (int j = 0; j < 8; j++)
        pk.c[j] = (signed char)(int)rintf(fminf(fmaxf(xm[j] / scale, -127.f), 127.f));
    const size_t addr = ((size_t)(row >> 5) * (D_DIM / 16) + (threadIdx.x >> 1)) * 512
                        + (row & 31) * 16 + (threadIdx.x & 1) * 8;
    *(int2*)(qbase + addr) = pk.v;
    if (threadIdx.x == 0) *srow = scale;
}

// ------- token shift + both LN/quant (packed) + out2 passthrough, full BT -------
__global__ void act_prep(const float* __restrict__ x,
                         const float* __restrict__ muk,
                         const float* __restrict__ gk, const float* __restrict__ bk,
                         const float* __restrict__ mur,
                         const float* __restrict__ gr, const float* __restrict__ br,
                         signed char* __restrict__ qk, float* __restrict__ sk,
                         signed char* __restrict__ qr, float* __restrict__ sr,
                         float* __restrict__ out2) {
    __shared__ float red[16];
    const int row = blockIdx.x;
    const int t = row & (T_LEN - 1);
    const int base = threadIdx.x * 8;

    float xv[8], xp[8];
    f32x4 xa = *(const f32x4*)(x + (size_t)row * D_DIM + base);
    f32x4 xb = *(const f32x4*)(x + (size_t)row * D_DIM + base + 4);
    xv[0]=xa[0]; xv[1]=xa[1]; xv[2]=xa[2]; xv[3]=xa[3];
    xv[4]=xb[0]; xv[5]=xb[1]; xv[6]=xb[2]; xv[7]=xb[3];
    if (t > 0) {
        f32x4 pa = *(const f32x4*)(x + (size_t)(row - 1) * D_DIM + base);
        f32x4 pb = *(const f32x4*)(x + (size_t)(row - 1) * D_DIM + base + 4);
        xp[0]=pa[0]; xp[1]=pa[1]; xp[2]=pa[2]; xp[3]=pa[3];
        xp[4]=pb[0]; xp[5]=pb[1]; xp[6]=pb[2]; xp[7]=pb[3];
    } else {
        #pragma unroll
        for (int j = 0; j < 8; j++) xp[j] = 0.f;
    }
    if (t == T_LEN - 1) {
        const int bb = row / T_LEN;
        *(f32x4*)(out2 + (size_t)bb * D_DIM + base)     = xa;
        *(f32x4*)(out2 + (size_t)bb * D_DIM + base + 4) = xb;
    }
    float mk[8], mr[8], xmk[8], xmr[8];
    f32x4 mka = *(const f32x4*)(muk + base), mkb = *(const f32x4*)(muk + base + 4);
    f32x4 mra = *(const f32x4*)(mur + base), mrb = *(const f32x4*)(mur + base + 4);
    mk[0]=mka[0]; mk[1]=mka[1]; mk[2]=mka[2]; mk[3]=mka[3];
    mk[4]=mkb[0]; mk[5]=mkb[1]; mk[6]=mkb[2]; mk[7]=mkb[3];
    mr[0]=mra[0]; mr[1]=mra[1]; mr[2]=mra[2]; mr[3]=mra[3];
    mr[4]=mrb[0]; mr[5]=mrb[1]; mr[6]=mrb[2]; mr[7]=mrb[3];
    #pragma unroll
    for (int j = 0; j < 8; j++) {
        const float dx = xp[j] - xv[j];
        xmk[j] = xv[j] + dx * mk[j];
        xmr[j] = xv[j] + dx * mr[j];
    }
    ln_quant8(xmk, gk, bk, qk, row, sk + row, red);
    ln_quant8(xmr, gr, br, qr, row, sr + row, red);
}

// -------- LN + act quant over H=8192 (k_act bf16, row-major in; packed int8 out) ----
__global__ void lnq_v(const unsigned short* __restrict__ kact,
                      const float* __restrict__ g, const float* __restrict__ b,
                      signed char* __restrict__ qv, float* __restrict__ sv) {
    __shared__ float red[16];
    const int row = blockIdx.x;
    const int base = threadIdx.x * 32;
    const unsigned short* kr = kact + (size_t)row * H_DIM + base;

    float v[32];
    float s = 0.f;
    #pragma unroll
    for (int c = 0; c < 4; c++) {
        ushort8 a = *(const ushort8*)(kr + c * 8);
        #pragma unroll
        for (int j = 0; j < 8; j++) { v[c * 8 + j] = bf2f(a[j]); s += v[c * 8 + j]; }
    }
    const float mean = block_sum(s, red) * (1.f / H_DIM);
    float s2 = 0.f;
    #pragma unroll
    for (int j = 0; j < 32; j++) { float d = v[j] - mean; s2 += d * d; }
    const float var  = block_sum(s2, red) * (1.f / H_DIM);
    const float rstd = 1.f / sqrtf(var + 1e-5f);
    float sa = 0.f;
    #pragma unroll
    for (int c = 0; c < 8; c++) {
        f32x4 ga = *(const f32x4*)(g + base + c * 4);
        f32x4 ba = *(const f32x4*)(b + base + c * 4);
        #pragma unroll
        for (int j = 0; j < 4; j++) {
            int k = c * 4 + j;
            v[k] = (v[k] - mean) * rstd * ga[j] + ba[j];
            sa += fabsf(v[k]);
        }
    }
    const float amean = block_sum(sa, red) * (1.f / H_DIM);
    const float scale = fmaxf(amean, 1e-8f) * 2.5f / 127.0f;
    union { signed char c[32]; i32x4v v4[2]; } pk;
    #pragma unroll
    for (int j = 0; j < 32; j++)
        pk.c[j] = (signed char)(int)rintf(fminf(fmaxf(v[j] / scale, -127.f), 127.f));
    const size_t tb = ((size_t)(row >> 5) * (H_DIM / 16) + threadIdx.x * 2) * 512
                      + (row & 31) * 16;
    *(i32x4v*)(qv + tb)       = pk.v4[0];
    *(i32x4v*)(qv + tb + 512) = pk.v4[1];
    if (threadIdx.x == 0) sv[row] = scale;
}

// ======== gemmF: fine-phase (m201-style) i8 MFMA GEMM, packed-A registers ========
// C[m,n] = sa[m]*sw * sum_k A[m,k]*B[n,k].  Tile 256x128, 512 thr = 8 waves as
// 2(M) x 4(N): wave covers rows [wr*128, +128) (MT=4 frags) x cols [wc*32, +32).
// B-frag LDS reads: only 2 waves share each byte (was 8 -> LDS traffic /4).
// Body = 128 k-bytes, 2 phases; each phase (m201 template):
//   { ds_read 2 b128 (this phase's B)  ||  loadA(t+1)/stage p(t+2) }
//   -> s_barrier -> lgkmcnt(0)+sched_barrier -> setprio1; 8 MFMA; setprio0 -> s_barrier
// B staged TWO bodies ahead into 3-buffer rotation (3x16KB); one counted vmcnt per
// body at end of ph1: queue [p(t+1):2][A(t+1):16][p(t+2):2] -> vmcnt(18) forces
// p(t+1) (16 at t=NB-2; skipped at t=NB-1).  WAR: buf t%3 rewritten during body t+1,
// after body t's final barrier which post-dates all lgkm-complete reads of it.
// Swizzle: 8-slot involution f(r)=r&7 (r6/r9-verified); packed-A layout r13-verified.
// EP: 0 = relu(v)^2 -> bf16;  1 = sigmoid(v) -> bf16;  2 = out_f32 = bf16gate * v.
template <int EP>
__global__ __launch_bounds__(512, 2) void gemmF(
    const signed char* __restrict__ Ap, const signed char* __restrict__ B,
    int K, int Nn, int gn,
    const float* __restrict__ sa, const float* __restrict__ swp,
    const unsigned short* __restrict__ gate_bf, float* __restrict__ out_f,
    unsigned short* __restrict__ out_bf) {
    __shared__ signed char Bs[3][16384];
    const int tid = threadIdx.x;
    const int nwg = gridDim.x, q8 = nwg >> 3;     // nwg % 8 == 0 (host guarantees)
    const int swz = (blockIdx.x & 7) * q8 + (blockIdx.x >> 3);
    const int bm = swz / gn, bn = swz % gn;
    const int lane = tid & 63, wave = tid >> 6;
    const int wr = wave >> 2, wc = wave & 3;
    const int lrow = lane & 31, lhalf = lane >> 5;
    const int KS = K >> 4;
    const size_t brow0 = (size_t)bn * 128;
    const int NB = K >> 7;                         // 16 or 64 (even)

    i32x16v acc[4] = {};

    auto stageB = [&](int p, int t, int j) {
        const int o = j * 512 + tid;               // 0..1023 over 2 passes
        const int r = o >> 3, sl = o & 7;          // 128 rows x 8 slots
        const signed char* g = B + (brow0 + r) * (size_t)K + t * 128
                               + ((sl ^ (r & 7)) * 16);
        __builtin_amdgcn_global_load_lds(
            (const __attribute__((address_space(1))) void*)g,
            (__attribute__((address_space(3))) void*)(&Bs[p][o * 16]), 16, 0, 0);
    };
    auto loadA = [&](i32x4v (&a)[4][2][2], int t) {
        #pragma unroll
        for (int tm = 0; tm < 4; tm++) {
            const size_t rt = (size_t)(bm * 8 + wr * 4 + tm) * KS;
            const signed char* bp = Ap + ((rt + (size_t)t * 8) << 9) + lane * 16;
            #pragma unroll
            for (int s = 0; s < 2; s++)
                #pragma unroll
                for (int sl = 0; sl < 2; sl++)
                    a[tm][s][sl] = *(const i32x4v*)(bp + (size_t)(s * 4 + sl * 2) * 512);
        }
    };

    // one phase: ds_read this subtile's B, then (caller already issued vmem),
    // barrier -> lgkm0 -> MFMA cluster -> barrier.
    auto phase = [&](int p, int s, i32x4v (&aC)[4][2][2]) {
        i32x4v b[2];
        const int r = wc * 32 + lrow;
        #pragma unroll
        for (int sl = 0; sl < 2; sl++) {
            const int slot = s * 4 + sl * 2 + lhalf;
            b[sl] = *(const i32x4v*)(&Bs[p][r * 128 + ((slot ^ (r & 7)) * 16)]);
        }
        __builtin_amdgcn_s_barrier();
        asm volatile("s_waitcnt lgkmcnt(0)" ::: "memory");
        __builtin_amdgcn_sched_barrier(0);
        __builtin_amdgcn_s_setprio(1);
        #pragma unroll
        for (int sl = 0; sl < 2; sl++)
            #pragma unroll
            for (int tm = 0; tm < 4; tm++)
                acc[tm] = __builtin_amdgcn_mfma_i32_32x32x32_i8(
                    aC[tm][s][sl], b[sl], acc[tm], 0, 0, 0);
        __builtin_amdgcn_s_setprio(0);
        __builtin_amdgcn_sched_barrier(0);
        __builtin_amdgcn_s_barrier();
    };

    i32x4v aE[4][2][2], aO[4][2][2];
    // prologue FIFO: p(0) x2, A(0) x16, p(1) x2  -> wait vmcnt(18) forces p(0)
    stageB(0, 0, 0); stageB(0, 0, 1);
    loadA(aE, 0);
    stageB(1, 1, 0); stageB(1, 1, 1);
    asm volatile("s_waitcnt vmcnt(18)" ::: "memory");
    __builtin_amdgcn_sched_barrier(0);
    __builtin_amdgcn_s_barrier();

    auto body = [&](int t, i32x4v (&aC)[4][2][2], i32x4v (&aN)[4][2][2]) {
        const int p = t % 3;
        const bool hasA = (t + 1 < NB);
        const bool hasB = (t + 2 < NB);
        // ph0: issue next-body A and first stage pass, then phase
        if (hasA) loadA(aN, t + 1);
        if (hasB) stageB((t + 2) % 3, t + 2, 0);
        phase(p, 0, aC);
        // ph1: second stage pass, counted wait for buf t+1, then phase
        if (hasB) stageB((t + 2) % 3, t + 2, 1);
        if (hasA) {
            if (hasB) asm volatile("s_waitcnt vmcnt(18)" ::: "memory");
            else      asm volatile("s_waitcnt vmcnt(16)" ::: "memory");
            __builtin_amdgcn_sched_barrier(0);
        }
        phase(p, 1, aC);
    };

    for (int t = 0; t < NB; t += 2) {
        body(t, aE, aO);
        body(t + 1, aO, aE);
    }

    const float sw = *swp;
    #pragma unroll
    for (int tm = 0; tm < 4; tm++) {
        #pragma unroll
        for (int rg = 0; rg < 16; rg++) {
            const int rin  = (rg & 3) + 8 * (rg >> 2) + 4 * lhalf;
            const int grow = bm * 256 + wr * 128 + tm * 32 + rin;
            const int gcol = bn * 128 + wc * 32 + lrow;
            const float v = (float)acc[tm][rg] * sa[grow] * sw;
            const size_t idx = (size_t)grow * Nn + gcol;
            if (EP == 0) {
                float rv = fmaxf(v, 0.f);
                out_bf[idx] = f2bf(rv * rv);
            } else if (EP == 1) {
                out_bf[idx] = f2bf(1.0f / (1.0f + expf(-v)));
            } else {
                out_f[idx] = bf2f(gate_bf[idx]) * v;
            }
        }
    }
}

extern "C" void kernel_launch(void* const* d_in, const int* in_sizes, int n_in,
                              void* d_out, int out_size, void* d_ws, size_t ws_size,
                              hipStream_t stream) {
    const float* x   = (const float*)d_in[0];
    const float* muk = (const float*)d_in[1];
    const float* mur = (const float*)d_in[2];
    const float* wk  = (const float*)d_in[3];
    const float* gk  = (const float*)d_in[4];
    const float* bk  = (const float*)d_in[5];
    const float* wr  = (const float*)d_in[6];
    const float* gr  = (const float*)d_in[7];
    const float* br  = (const float*)d_in[8];
    const float* wv  = (const float*)d_in[9];
    const float* gv  = (const float*)d_in[10];
    const float* bv  = (const float*)d_in[11];

    // ---- adaptive workspace layout (pure function of ws_size) ----
    char* wsb = (char*)d_ws;
    size_t off = 0;
    auto alloc = [&](size_t bytes) -> size_t {
        size_t p = off;
        off = (off + bytes + 255) & ~(size_t)255;
        return p;
    };
    const size_t o_wqk  = alloc((size_t)H_DIM * D_DIM);
    const size_t o_wqr  = alloc((size_t)D_DIM * D_DIM);
    const size_t o_wqv  = alloc((size_t)D_DIM * H_DIM);
    const size_t o_wsc  = alloc(64);
    const size_t o_part = alloc(3 * 1024 * sizeof(float));
    const size_t o_xqk  = alloc((size_t)BT * D_DIM);        // packed
    const size_t o_xqr  = alloc((size_t)BT * D_DIM);        // packed
    const size_t o_gate = alloc((size_t)BT * D_DIM * 2);    // bf16, row-major
    const size_t o_sk   = alloc((size_t)BT * 4);
    const size_t o_sr   = alloc((size_t)BT * 4);
    const size_t fixed  = off;

    int CH = BT;
    while (CH > 512 &&
           fixed + (size_t)CH * (H_DIM + 2 * H_DIM + 4) + 8192 > ws_size)
        CH >>= 1;
    const size_t o_xqv  = alloc((size_t)CH * H_DIM);        // packed
    const size_t o_kact = alloc((size_t)CH * H_DIM * 2);    // bf16, row-major
    const size_t o_sv   = alloc((size_t)CH * 4);

    signed char* wqk = (signed char*)(wsb + o_wqk);
    signed char* wqr = (signed char*)(wsb + o_wqr);
    signed char* wqv = (signed char*)(wsb + o_wqv);
    float* wsc  = (float*)(wsb + o_wsc);
    float* part = (float*)(wsb + o_part);
    signed char* xqk = (signed char*)(wsb + o_xqk);
    signed char* xqr = (signed char*)(wsb + o_xqr);
    unsigned short* gate = (unsigned short*)(wsb + o_gate);
    float* sk = (float*)(wsb + o_sk);
    float* sr = (float*)(wsb + o_sr);
    signed char* xqv = (signed char*)(wsb + o_xqv);
    unsigned short* kact = (unsigned short*)(wsb + o_kact);
    float* sv = (float*)(wsb + o_sv);

    float* outp = (float*)d_out;
    float* out2 = outp + (size_t)BT * D_DIM;

    // ---- fused weight prep ----
    wabs_all<<<3072, 256, 0, stream>>>(wk, wr, wv, part);
    wfinal_all<<<3, 256, 0, stream>>>(part, wsc);
    wquant_all<<<5120, 256, 0, stream>>>(wk, wr, wv, wqk, wqr, wqv, wsc);

    // ---- token shift + LN + act quant (packed), full BT ----
    act_prep<<<BT, 256, 0, stream>>>(x, muk, gk, bk, mur, gr, br,
                                     xqk, sk, xqr, sr, out2);

    // gate = sigmoid(bitlinear_r) -> bf16, full BT   [256x128, grid 512]
    gemmF<1><<<(BT / 256) * (D_DIM / 128), 512, 0, stream>>>(
        xqr, wqr, D_DIM, D_DIM, D_DIM / 128, sr, wsc + 1,
        (const unsigned short*)nullptr, (float*)nullptr, gate);

    // ---- row-chunked: kact -> lnq_v -> out ----
    for (int row0 = 0; row0 < BT; row0 += CH) {
        // kact = relu(bitlinear_k)^2 -> bf16   [256x128, grid (CH/256)*64]
        gemmF<0><<<(CH / 256) * (H_DIM / 128), 512, 0, stream>>>(
            xqk + (size_t)row0 * D_DIM, wqk, D_DIM, H_DIM, H_DIM / 128,
            sk + row0, wsc + 0,
            (const unsigned short*)nullptr, (float*)nullptr, kact);

        lnq_v<<<CH, 256, 0, stream>>>(kact, gv, bv, xqv, sv);

        // out = bf16(gate) * bitlinear_v  (f32 -> d_out)   [256x128, grid (CH/256)*16]
        gemmF<2><<<(CH / 256) * (D_DIM / 128), 512, 0, stream>>>(
            xqv, wqv, H_DIM, D_DIM, D_DIM / 128, sv, wsc + 2,
            gate + (size_t)row0 * D_DIM, outp + (size_t)row0 * D_DIM,
            (unsigned short*)nullptr);
    }
}

// Round 16
// 769.681 us; speedup vs baseline: 1.0570x; 1.0570x over previous
//
#include <hip/hip_runtime.h>

// ---------------- problem constants ----------------
#define T_LEN 2048
#define B_SZ  4
#define D_DIM 2048
#define H_DIM 8192
#define BT    (B_SZ * T_LEN)

typedef float f32x4 __attribute__((ext_vector_type(4)));
typedef int   i32x4v __attribute__((ext_vector_type(4)));
typedef int   i32x16v __attribute__((ext_vector_type(16)));
typedef unsigned short ushort8 __attribute__((ext_vector_type(8)));

__device__ __forceinline__ float bf2f(unsigned short u) {
    unsigned int i = ((unsigned int)u) << 16;
    return __builtin_bit_cast(float, i);
}
__device__ __forceinline__ unsigned short f2bf(float f) {
    unsigned int i = __builtin_bit_cast(unsigned int, f);
    i += 0x7fffu + ((i >> 16) & 1u);   // RNE
    return (unsigned short)(i >> 16);
}

// ---------------- block reduction (blockDim == 256) ----------------
__device__ __forceinline__ float block_sum(float v, float* red) {
    #pragma unroll
    for (int o = 32; o > 0; o >>= 1) v += __shfl_down(v, o, 64);
    const int lane = threadIdx.x & 63, w = threadIdx.x >> 6;
    if (lane == 0) red[w] = v;
    __syncthreads();
    float r = red[0] + red[1] + red[2] + red[3];
    __syncthreads();
    return r;
}

// ---------------- fused weight-prep ----------------
__global__ void wabs_all(const float* __restrict__ wk, const float* __restrict__ wr,
                         const float* __restrict__ wv, float* __restrict__ part) {
    __shared__ float red[16];
    const int m = blockIdx.x >> 10;
    const int blk = blockIdx.x & 1023;
    const float* w = (m == 0) ? wk : (m == 1) ? wr : wv;
    const int n = (m == 1) ? D_DIM * D_DIM : H_DIM * D_DIM;
    float s = 0.f;
    int i = (blk * 256 + threadIdx.x) * 8;
    const int stride = 1024 * 256 * 8;
    for (; i < n; i += stride) {
        f32x4 a = *(const f32x4*)(w + i);
        f32x4 b = *(const f32x4*)(w + i + 4);
        #pragma unroll
        for (int j = 0; j < 4; j++) s += fabsf(a[j]) + fabsf(b[j]);
    }
    float tot = block_sum(s, red);
    if (threadIdx.x == 0) part[blockIdx.x] = tot;
}

__global__ void wfinal_all(const float* __restrict__ part, float* __restrict__ wsc) {
    __shared__ float red[16];
    const int m = blockIdx.x;
    const int n = (m == 1) ? D_DIM * D_DIM : H_DIM * D_DIM;
    float s = 0.f;
    for (int i = threadIdx.x; i < 1024; i += 256) s += part[m * 1024 + i];
    float tot = block_sum(s, red);
    if (threadIdx.x == 0) wsc[m] = fmaxf(tot / (float)n, 1e-8f);
}

__global__ void wquant_all(const float* __restrict__ wk, const float* __restrict__ wr,
                           const float* __restrict__ wv,
                           signed char* __restrict__ qk, signed char* __restrict__ qr,
                           signed char* __restrict__ qv,
                           const float* __restrict__ wsc) {
    const int b = blockIdx.x;
    int m, blk, nblk;
    if (b < 2048)      { m = 0; blk = b;        nblk = 2048; }
    else if (b < 3072) { m = 1; blk = b - 2048; nblk = 1024; }
    else               { m = 2; blk = b - 3072; nblk = 2048; }
    const float* w = (m == 0) ? wk : (m == 1) ? wr : wv;
    signed char* q = (m == 0) ? qk : (m == 1) ? qr : qv;
    const int n = (m == 1) ? D_DIM * D_DIM : H_DIM * D_DIM;
    const float s = wsc[m];
    int i = (blk * 256 + threadIdx.x) * 16;
    const int stride = nblk * 256 * 16;
    for (; i < n; i += stride) {
        union { signed char c[16]; i32x4v v; } pk;
        #pragma unroll
        for (int h = 0; h < 4; h++) {
            f32x4 a = *(const f32x4*)(w + i + h * 4);
            #pragma unroll
            for (int j = 0; j < 4; j++)
                pk.c[h * 4 + j] =
                    (signed char)(int)rintf(fminf(fmaxf(a[j] / s, -1.f), 1.f));
        }
        *(i32x4v*)(q + i) = pk.v;
    }
}

// ---------------- LN + act quant, PACKED-fragment output ----------------
// Packed layout: byte of (row r, k) at ((r>>5)*(K/16) + k/16)*512 + (r&31)*16 + (k%16).
__device__ __forceinline__ void ln_quant8(const float* xm_in,
                                          const float* __restrict__ g,
                                          const float* __restrict__ b,
                                          signed char* qbase, int row,
                                          float* srow, float* red) {
    const int base = threadIdx.x * 8;
    float xm[8];
    float s = 0.f;
    #pragma unroll
    for (int j = 0; j < 8; j++) { xm[j] = xm_in[j]; s += xm[j]; }
    const float mean = block_sum(s, red) * (1.f / D_DIM);
    float s2 = 0.f;
    #pragma unroll
    for (int j = 0; j < 8; j++) { float d = xm[j] - mean; s2 += d * d; }
    const float var  = block_sum(s2, red) * (1.f / D_DIM);
    const float rstd = 1.f / sqrtf(var + 1e-5f);
    f32x4 ga = *(const f32x4*)(g + base), gb = *(const f32x4*)(g + base + 4);
    f32x4 ba = *(const f32x4*)(b + base), bb2 = *(const f32x4*)(b + base + 4);
    float gg[8] = {ga[0],ga[1],ga[2],ga[3],gb[0],gb[1],gb[2],gb[3]};
    float bb[8] = {ba[0],ba[1],ba[2],ba[3],bb2[0],bb2[1],bb2[2],bb2[3]};
    float sa = 0.f;
    #pragma unroll
    for (int j = 0; j < 8; j++) {
        xm[j] = (xm[j] - mean) * rstd * gg[j] + bb[j];
        sa += fabsf(xm[j]);
    }
    const float amean = block_sum(sa, red) * (1.f / D_DIM);
    const float scale = fmaxf(amean, 1e-8f) * 2.5f / 127.0f;
    union { signed char c[8]; int2 v; } pk;
    #pragma unroll
    for (int j = 0; j < 8; j++)
        pk.c[j] = (signed char)(int)rintf(fminf(fmaxf(xm[j] / scale, -127.f), 127.f));
    const size_t addr = ((size_t)(row >> 5) * (D_DIM / 16) + (threadIdx.x >> 1)) * 512
                        + (row & 31) * 16 + (threadIdx.x & 1) * 8;
    *(int2*)(qbase + addr) = pk.v;
    if (threadIdx.x == 0) *srow = scale;
}

// ------- token shift + both LN/quant (packed) + out2 passthrough, full BT -------
__global__ void act_prep(const float* __restrict__ x,
                         const float* __restrict__ muk,
                         const float* __restrict__ gk, const float* __restrict__ bk,
                         const float* __restrict__ mur,
                         const float* __restrict__ gr, const float* __restrict__ br,
                         signed char* __restrict__ qk, float* __restrict__ sk,
                         signed char* __restrict__ qr, float* __restrict__ sr,
                         float* __restrict__ out2) {
    __shared__ float red[16];
    const int row = blockIdx.x;
    const int t = row & (T_LEN - 1);
    const int base = threadIdx.x * 8;

    float xv[8], xp[8];
    f32x4 xa = *(const f32x4*)(x + (size_t)row * D_DIM + base);
    f32x4 xb = *(const f32x4*)(x + (size_t)row * D_DIM + base + 4);
    xv[0]=xa[0]; xv[1]=xa[1]; xv[2]=xa[2]; xv[3]=xa[3];
    xv[4]=xb[0]; xv[5]=xb[1]; xv[6]=xb[2]; xv[7]=xb[3];
    if (t > 0) {
        f32x4 pa = *(const f32x4*)(x + (size_t)(row - 1) * D_DIM + base);
        f32x4 pb = *(const f32x4*)(x + (size_t)(row - 1) * D_DIM + base + 4);
        xp[0]=pa[0]; xp[1]=pa[1]; xp[2]=pa[2]; xp[3]=pa[3];
        xp[4]=pb[0]; xp[5]=pb[1]; xp[6]=pb[2]; xp[7]=pb[3];
    } else {
        #pragma unroll
        for (int j = 0; j < 8; j++) xp[j] = 0.f;
    }
    if (t == T_LEN - 1) {
        const int bb = row / T_LEN;
        *(f32x4*)(out2 + (size_t)bb * D_DIM + base)     = xa;
        *(f32x4*)(out2 + (size_t)bb * D_DIM + base + 4) = xb;
    }
    float mk[8], mr[8], xmk[8], xmr[8];
    f32x4 mka = *(const f32x4*)(muk + base), mkb = *(const f32x4*)(muk + base + 4);
    f32x4 mra = *(const f32x4*)(mur + base), mrb = *(const f32x4*)(mur + base + 4);
    mk[0]=mka[0]; mk[1]=mka[1]; mk[2]=mka[2]; mk[3]=mka[3];
    mk[4]=mkb[0]; mk[5]=mkb[1]; mk[6]=mkb[2]; mk[7]=mkb[3];
    mr[0]=mra[0]; mr[1]=mra[1]; mr[2]=mra[2]; mr[3]=mra[3];
    mr[4]=mrb[0]; mr[5]=mrb[1]; mr[6]=mrb[2]; mr[7]=mrb[3];
    #pragma unroll
    for (int j = 0; j < 8; j++) {
        const float dx = xp[j] - xv[j];
        xmk[j] = xv[j] + dx * mk[j];
        xmr[j] = xv[j] + dx * mr[j];
    }
    ln_quant8(xmk, gk, bk, qk, row, sk + row, red);
    ln_quant8(xmr, gr, br, qr, row, sr + row, red);
}

// -------- LN + act quant over H=8192 (k_act bf16, row-major in; packed int8 out) ----
__global__ void lnq_v(const unsigned short* __restrict__ kact,
                      const float* __restrict__ g, const float* __restrict__ b,
                      signed char* __restrict__ qv, float* __restrict__ sv) {
    __shared__ float red[16];
    const int row = blockIdx.x;
    const int base = threadIdx.x * 32;
    const unsigned short* kr = kact + (size_t)row * H_DIM + base;

    float v[32];
    float s = 0.f;
    #pragma unroll
    for (int c = 0; c < 4; c++) {
        ushort8 a = *(const ushort8*)(kr + c * 8);
        #pragma unroll
        for (int j = 0; j < 8; j++) { v[c * 8 + j] = bf2f(a[j]); s += v[c * 8 + j]; }
    }
    const float mean = block_sum(s, red) * (1.f / H_DIM);
    float s2 = 0.f;
    #pragma unroll
    for (int j = 0; j < 32; j++) { float d = v[j] - mean; s2 += d * d; }
    const float var  = block_sum(s2, red) * (1.f / H_DIM);
    const float rstd = 1.f / sqrtf(var + 1e-5f);
    float sa = 0.f;
    #pragma unroll
    for (int c = 0; c < 8; c++) {
        f32x4 ga = *(const f32x4*)(g + base + c * 4);
        f32x4 ba = *(const f32x4*)(b + base + c * 4);
        #pragma unroll
        for (int j = 0; j < 4; j++) {
            int k = c * 4 + j;
            v[k] = (v[k] - mean) * rstd * ga[j] + ba[j];
            sa += fabsf(v[k]);
        }
    }
    const float amean = block_sum(sa, red) * (1.f / H_DIM);
    const float scale = fmaxf(amean, 1e-8f) * 2.5f / 127.0f;
    union { signed char c[32]; i32x4v v4[2]; } pk;
    #pragma unroll
    for (int j = 0; j < 32; j++)
        pk.c[j] = (signed char)(int)rintf(fminf(fmaxf(v[j] / scale, -127.f), 127.f));
    const size_t tb = ((size_t)(row >> 5) * (H_DIM / 16) + threadIdx.x * 2) * 512
                      + (row & 31) * 16;
    *(i32x4v*)(qv + tb)       = pk.v4[0];
    *(i32x4v*)(qv + tb + 512) = pk.v4[1];
    if (threadIdx.x == 0) sv[row] = scale;
}

// ======== gemmM: r13 coarse-sync skeleton + MT=4/TN=1 wave geometry ========
// C[m,n] = sa[m]*sw * sum_k A[m,k]*B[n,k].  Tile 256x128, 512 thr = 8 waves as
// 2(M) x 4(N): wave = 128 rows (MT=4 frags) x 32 cols (TN=1).  One B fragment
// feeds 4 MFMAs -> per-body B LDS reads = 16 KB vs MFMA 1170 cyc (3:1 MFMA-bound).
// Body = 128 k-bytes (2 sub-tiles of 64); ONE barrier + ONE counted vmcnt per body.
// B: 3-buffer rotation (3x16KB LDS), staged 1 body ahead (2 gload_lds passes);
// swizzle f(r)=r&7 on 8 slots (r6/r9-verified involution; linear dest +
// inverse-swz global src + swz ds_read).  A: packed-fragment registers
// (r13-verified layout), double-buffered aE/aO (loadA after barrier, tracked deps).
// FIFO at wait: [B(t):2][A(t):16][B(t+1):2] -> vmcnt(18) forces exactly B(t);
// prologue pre-stages B(0),A(0),B(1) giving same count at t=0; tail vmcnt(0).
// WAR: buf (t+1)%3 written at body t; its previous read was body t-2, separated
// by barrier(t-1) -> safe.
// EP: 0 = relu(v)^2 -> bf16;  1 = sigmoid(v) -> bf16;  2 = out_f32 = bf16gate * v.
template <int EP>
__global__ __launch_bounds__(512, 2) void gemmM(
    const signed char* __restrict__ Ap, const signed char* __restrict__ B,
    int K, int Nn, int gn,
    const float* __restrict__ sa, const float* __restrict__ swp,
    const unsigned short* __restrict__ gate_bf, float* __restrict__ out_f,
    unsigned short* __restrict__ out_bf) {
    __shared__ signed char Bs[3][16384];
    const int tid = threadIdx.x;
    const int nwg = gridDim.x, q8 = nwg >> 3;     // nwg % 8 == 0 (host guarantees)
    const int swz = (blockIdx.x & 7) * q8 + (blockIdx.x >> 3);
    const int bm = swz / gn, bn = swz % gn;
    const int lane = tid & 63, wave = tid >> 6;
    const int wr = wave >> 2, wc = wave & 3;       // 2(M) x 4(N)
    const int lrow = lane & 31, lhalf = lane >> 5;
    const int KS = K >> 4;
    const size_t brow0 = (size_t)bn * 128;
    const int NB = K >> 7;                         // 16 or 64 (even)

    i32x16v acc[4] = {};

    auto stageB = [&](int p, int t) {
        #pragma unroll
        for (int j = 0; j < 2; j++) {
            const int o = j * 512 + tid;           // 0..1023
            const int r = o >> 3, sl = o & 7;      // 128 rows x 8 slots
            const signed char* g = B + (brow0 + r) * (size_t)K + t * 128
                                   + ((sl ^ (r & 7)) * 16);
            __builtin_amdgcn_global_load_lds(
                (const __attribute__((address_space(1))) void*)g,
                (__attribute__((address_space(3))) void*)(&Bs[p][o * 16]), 16, 0, 0);
        }
    };
    auto loadA = [&](i32x4v (&a)[4][2][2], int t) {
        #pragma unroll
        for (int tm = 0; tm < 4; tm++) {
            const size_t rt = (size_t)(bm * 8 + wr * 4 + tm) * KS;
            const signed char* bp = Ap + ((rt + (size_t)t * 8) << 9) + lane * 16;
            #pragma unroll
            for (int s = 0; s < 2; s++)
                #pragma unroll
                for (int sl = 0; sl < 2; sl++)
                    a[tm][s][sl] = *(const i32x4v*)(bp + (size_t)(s * 4 + sl * 2) * 512);
        }
    };

    auto bodyf = [&](int t, i32x4v (&aC)[4][2][2], i32x4v (&aN)[4][2][2]) {
        const bool pf = (t + 1 < NB);
        if (t > 0 && pf) stageB((t + 1) % 3, t + 1);
        if (pf) asm volatile("s_waitcnt vmcnt(18)" ::: "memory");
        else    asm volatile("s_waitcnt vmcnt(0)" ::: "memory");
        __builtin_amdgcn_sched_barrier(0);
        __builtin_amdgcn_s_barrier();              // buf t%3 ready for all waves
        __builtin_amdgcn_sched_barrier(0);
        if (pf) loadA(aN, t + 1);                  // compiler-tracked register deps
        const int p = t % 3;
        const int r = wc * 32 + lrow;
        #pragma unroll
        for (int s = 0; s < 2; s++) {
            i32x4v b[2];
            #pragma unroll
            for (int sl = 0; sl < 2; sl++) {
                const int slot = s * 4 + sl * 2 + lhalf;
                b[sl] = *(const i32x4v*)(&Bs[p][r * 128 + ((slot ^ (r & 7)) * 16)]);
            }
            __builtin_amdgcn_s_setprio(1);
            #pragma unroll
            for (int sl = 0; sl < 2; sl++)
                #pragma unroll
                for (int tm = 0; tm < 4; tm++)
                    acc[tm] = __builtin_amdgcn_mfma_i32_32x32x32_i8(
                        aC[tm][s][sl], b[sl], acc[tm], 0, 0, 0);
            __builtin_amdgcn_s_setprio(0);
        }
    };

    i32x4v aE[4][2][2], aO[4][2][2];
    // prologue FIFO: B(0):2, A(0):16, B(1):2
    stageB(0, 0);
    loadA(aE, 0);
    stageB(1, 1);
    for (int t = 0; t < NB; t += 2) {
        bodyf(t, aE, aO);
        bodyf(t + 1, aO, aE);
    }

    const float sw = *swp;
    #pragma unroll
    for (int tm = 0; tm < 4; tm++) {
        #pragma unroll
        for (int rg = 0; rg < 16; rg++) {
            const int rin  = (rg & 3) + 8 * (rg >> 2) + 4 * lhalf;
            const int grow = bm * 256 + wr * 128 + tm * 32 + rin;
            const int gcol = bn * 128 + wc * 32 + lrow;
            const float v = (float)acc[tm][rg] * sa[grow] * sw;
            const size_t idx = (size_t)grow * Nn + gcol;
            if (EP == 0) {
                float rv = fmaxf(v, 0.f);
                out_bf[idx] = f2bf(rv * rv);
            } else if (EP == 1) {
                out_bf[idx] = f2bf(1.0f / (1.0f + expf(-v)));
            } else {
                out_f[idx] = bf2f(gate_bf[idx]) * v;
            }
        }
    }
}

extern "C" void kernel_launch(void* const* d_in, const int* in_sizes, int n_in,
                              void* d_out, int out_size, void* d_ws, size_t ws_size,
                              hipStream_t stream) {
    const float* x   = (const float*)d_in[0];
    const float* muk = (const float*)d_in[1];
    const float* mur = (const float*)d_in[2];
    const float* wk  = (const float*)d_in[3];
    const float* gk  = (const float*)d_in[4];
    const float* bk  = (const float*)d_in[5];
    const float* wr  = (const float*)d_in[6];
    const float* gr  = (const float*)d_in[7];
    const float* br  = (const float*)d_in[8];
    const float* wv  = (const float*)d_in[9];
    const float* gv  = (const float*)d_in[10];
    const float* bv  = (const float*)d_in[11];

    // ---- adaptive workspace layout (pure function of ws_size) ----
    char* wsb = (char*)d_ws;
    size_t off = 0;
    auto alloc = [&](size_t bytes) -> size_t {
        size_t p = off;
        off = (off + bytes + 255) & ~(size_t)255;
        return p;
    };
    const size_t o_wqk  = alloc((size_t)H_DIM * D_DIM);
    const size_t o_wqr  = alloc((size_t)D_DIM * D_DIM);
    const size_t o_wqv  = alloc((size_t)D_DIM * H_DIM);
    const size_t o_wsc  = alloc(64);
    const size_t o_part = alloc(3 * 1024 * sizeof(float));
    const size_t o_xqk  = alloc((size_t)BT * D_DIM);        // packed
    const size_t o_xqr  = alloc((size_t)BT * D_DIM);        // packed
    const size_t o_gate = alloc((size_t)BT * D_DIM * 2);    // bf16, row-major
    const size_t o_sk   = alloc((size_t)BT * 4);
    const size_t o_sr   = alloc((size_t)BT * 4);
    const size_t fixed  = off;

    int CH = BT;
    while (CH > 512 &&
           fixed + (size_t)CH * (H_DIM + 2 * H_DIM + 4) + 8192 > ws_size)
        CH >>= 1;
    const size_t o_xqv  = alloc((size_t)CH * H_DIM);        // packed
    const size_t o_kact = alloc((size_t)CH * H_DIM * 2);    // bf16, row-major
    const size_t o_sv   = alloc((size_t)CH * 4);

    signed char* wqk = (signed char*)(wsb + o_wqk);
    signed char* wqr = (signed char*)(wsb + o_wqr);
    signed char* wqv = (signed char*)(wsb + o_wqv);
    float* wsc  = (float*)(wsb + o_wsc);
    float* part = (float*)(wsb + o_part);
    signed char* xqk = (signed char*)(wsb + o_xqk);
    signed char* xqr = (signed char*)(wsb + o_xqr);
    unsigned short* gate = (unsigned short*)(wsb + o_gate);
    float* sk = (float*)(wsb + o_sk);
    float* sr = (float*)(wsb + o_sr);
    signed char* xqv = (signed char*)(wsb + o_xqv);
    unsigned short* kact = (unsigned short*)(wsb + o_kact);
    float* sv = (float*)(wsb + o_sv);

    float* outp = (float*)d_out;
    float* out2 = outp + (size_t)BT * D_DIM;

    // ---- fused weight prep ----
    wabs_all<<<3072, 256, 0, stream>>>(wk, wr, wv, part);
    wfinal_all<<<3, 256, 0, stream>>>(part, wsc);
    wquant_all<<<5120, 256, 0, stream>>>(wk, wr, wv, wqk, wqr, wqv, wsc);

    // ---- token shift + LN + act quant (packed), full BT ----
    act_prep<<<BT, 256, 0, stream>>>(x, muk, gk, bk, mur, gr, br,
                                     xqk, sk, xqr, sr, out2);

    // gate = sigmoid(bitlinear_r) -> bf16, full BT   [256x128, grid 512]
    gemmM<1><<<(BT / 256) * (D_DIM / 128), 512, 0, stream>>>(
        xqr, wqr, D_DIM, D_DIM, D_DIM / 128, sr, wsc + 1,
        (const unsigned short*)nullptr, (float*)nullptr, gate);

    // ---- row-chunked: kact -> lnq_v -> out ----
    for (int row0 = 0; row0 < BT; row0 += CH) {
        // kact = relu(bitlinear_k)^2 -> bf16   [256x128, grid (CH/256)*64]
        gemmM<0><<<(CH / 256) * (H_DIM / 128), 512, 0, stream>>>(
            xqk + (size_t)row0 * D_DIM, wqk, D_DIM, H_DIM, H_DIM / 128,
            sk + row0, wsc + 0,
            (const unsigned short*)nullptr, (float*)nullptr, kact);

        lnq_v<<<CH, 256, 0, stream>>>(kact, gv, bv, xqv, sv);

        // out = bf16(gate) * bitlinear_v  (f32 -> d_out)   [256x128, grid (CH/256)*16]
        gemmM<2><<<(CH / 256) * (D_DIM / 128), 512, 0, stream>>>(
            xqv, wqv, H_DIM, D_DIM, D_DIM / 128, sv, wsc + 2,
            gate + (size_t)row0 * D_DIM, outp + (size_t)row0 * D_DIM,
            (unsigned short*)nullptr);
    }
}

// Round 17
// 599.279 us; speedup vs baseline: 1.3576x; 1.2843x over previous
//
#include <hip/hip_runtime.h>

// ---------------- problem constants ----------------
#define T_LEN 2048
#define B_SZ  4
#define D_DIM 2048
#define H_DIM 8192
#define BT    (B_SZ * T_LEN)

typedef float f32x4 __attribute__((ext_vector_type(4)));
typedef int   i32x4v __attribute__((ext_vector_type(4)));
typedef int   i32x16v __attribute__((ext_vector_type(16)));
typedef unsigned short ushort8 __attribute__((ext_vector_type(8)));

__device__ __forceinline__ float bf2f(unsigned short u) {
    unsigned int i = ((unsigned int)u) << 16;
    return __builtin_bit_cast(float, i);
}
__device__ __forceinline__ unsigned short f2bf(float f) {
    unsigned int i = __builtin_bit_cast(unsigned int, f);
    i += 0x7fffu + ((i >> 16) & 1u);   // RNE
    return (unsigned short)(i >> 16);
}

// ---------------- block reduction (blockDim == 256) ----------------
__device__ __forceinline__ float block_sum(float v, float* red) {
    #pragma unroll
    for (int o = 32; o > 0; o >>= 1) v += __shfl_down(v, o, 64);
    const int lane = threadIdx.x & 63, w = threadIdx.x >> 6;
    if (lane == 0) red[w] = v;
    __syncthreads();
    float r = red[0] + red[1] + red[2] + red[3];
    __syncthreads();
    return r;
}

// ---------------- fused weight-prep ----------------
__global__ void wabs_all(const float* __restrict__ wk, const float* __restrict__ wr,
                         const float* __restrict__ wv, float* __restrict__ part) {
    __shared__ float red[16];
    const int m = blockIdx.x >> 10;
    const int blk = blockIdx.x & 1023;
    const float* w = (m == 0) ? wk : (m == 1) ? wr : wv;
    const int n = (m == 1) ? D_DIM * D_DIM : H_DIM * D_DIM;
    float s = 0.f;
    int i = (blk * 256 + threadIdx.x) * 8;
    const int stride = 1024 * 256 * 8;
    for (; i < n; i += stride) {
        f32x4 a = *(const f32x4*)(w + i);
        f32x4 b = *(const f32x4*)(w + i + 4);
        #pragma unroll
        for (int j = 0; j < 4; j++) s += fabsf(a[j]) + fabsf(b[j]);
    }
    float tot = block_sum(s, red);
    if (threadIdx.x == 0) part[blockIdx.x] = tot;
}

__global__ void wfinal_all(const float* __restrict__ part, float* __restrict__ wsc) {
    __shared__ float red[16];
    const int m = blockIdx.x;
    const int n = (m == 1) ? D_DIM * D_DIM : H_DIM * D_DIM;
    float s = 0.f;
    for (int i = threadIdx.x; i < 1024; i += 256) s += part[m * 1024 + i];
    float tot = block_sum(s, red);
    if (threadIdx.x == 0) wsc[m] = fmaxf(tot / (float)n, 1e-8f);
}

__global__ void wquant_all(const float* __restrict__ wk, const float* __restrict__ wr,
                           const float* __restrict__ wv,
                           signed char* __restrict__ qk, signed char* __restrict__ qr,
                           signed char* __restrict__ qv,
                           const float* __restrict__ wsc) {
    const int b = blockIdx.x;
    int m, blk, nblk;
    if (b < 2048)      { m = 0; blk = b;        nblk = 2048; }
    else if (b < 3072) { m = 1; blk = b - 2048; nblk = 1024; }
    else               { m = 2; blk = b - 3072; nblk = 2048; }
    const float* w = (m == 0) ? wk : (m == 1) ? wr : wv;
    signed char* q = (m == 0) ? qk : (m == 1) ? qr : qv;
    const int n = (m == 1) ? D_DIM * D_DIM : H_DIM * D_DIM;
    const float s = wsc[m];
    int i = (blk * 256 + threadIdx.x) * 16;
    const int stride = nblk * 256 * 16;
    for (; i < n; i += stride) {
        union { signed char c[16]; i32x4v v; } pk;
        #pragma unroll
        for (int h = 0; h < 4; h++) {
            f32x4 a = *(const f32x4*)(w + i + h * 4);
            #pragma unroll
            for (int j = 0; j < 4; j++)
                pk.c[h * 4 + j] =
                    (signed char)(int)rintf(fminf(fmaxf(a[j] / s, -1.f), 1.f));
        }
        *(i32x4v*)(q + i) = pk.v;
    }
}

// ---------------- LN + act quant, PACKED-fragment output ----------------
// Packed layout: byte of (row r, k) at ((r>>5)*(K/16) + k/16)*512 + (r&31)*16 + (k%16).
__device__ __forceinline__ void ln_quant8(const float* xm_in,
                                          const float* __restrict__ g,
                                          const float* __restrict__ b,
                                          signed char* qbase, int row,
                                          float* srow, float* red) {
    const int base = threadIdx.x * 8;
    float xm[8];
    float s = 0.f;
    #pragma unroll
    for (int j = 0; j < 8; j++) { xm[j] = xm_in[j]; s += xm[j]; }
    const float mean = block_sum(s, red) * (1.f / D_DIM);
    float s2 = 0.f;
    #pragma unroll
    for (int j = 0; j < 8; j++) { float d = xm[j] - mean; s2 += d * d; }
    const float var  = block_sum(s2, red) * (1.f / D_DIM);
    const float rstd = 1.f / sqrtf(var + 1e-5f);
    f32x4 ga = *(const f32x4*)(g + base), gb = *(const f32x4*)(g + base + 4);
    f32x4 ba = *(const f32x4*)(b + base), bb2 = *(const f32x4*)(b + base + 4);
    float gg[8] = {ga[0],ga[1],ga[2],ga[3],gb[0],gb[1],gb[2],gb[3]};
    float bb[8] = {ba[0],ba[1],ba[2],ba[3],bb2[0],bb2[1],bb2[2],bb2[3]};
    float sa = 0.f;
    #pragma unroll
    for (int j = 0; j < 8; j++) {
        xm[j] = (xm[j] - mean) * rstd * gg[j] + bb[j];
        sa += fabsf(xm[j]);
    }
    const float amean = block_sum(sa, red) * (1.f / D_DIM);
    const float scale = fmaxf(amean, 1e-8f) * 2.5f / 127.0f;
    union { signed char c[8]; int2 v; } pk;
    #pragma unroll
    for (int j = 0; j < 8; j++)
        pk.c[j] = (signed char)(int)rintf(fminf(fmaxf(xm[j] / scale, -127.f), 127.f));
    const size_t addr = ((size_t)(row >> 5) * (D_DIM / 16) + (threadIdx.x >> 1)) * 512
                        + (row & 31) * 16 + (threadIdx.x & 1) * 8;
    *(int2*)(qbase + addr) = pk.v;
    if (threadIdx.x == 0) *srow = scale;
}

// ------- token shift + both LN/quant (packed) + out2 passthrough, full BT -------
__global__ void act_prep(const float* __restrict__ x,
                         const float* __restrict__ muk,
                         const float* __restrict__ gk, const float* __restrict__ bk,
                         const float* __restrict__ mur,
                         const float* __restrict__ gr, const float* __restrict__ br,
                         signed char* __restrict__ qk, float* __restrict__ sk,
                         signed char* __restrict__ qr, float* __restrict__ sr,
                         float* __restrict__ out2) {
    __shared__ float red[16];
    const int row = blockIdx.x;
    const int t = row & (T_LEN - 1);
    const int base = threadIdx.x * 8;

    float xv[8], xp[8];
    f32x4 xa = *(const f32x4*)(x + (size_t)row * D_DIM + base);
    f32x4 xb = *(const f32x4*)(x + (size_t)row * D_DIM + base + 4);
    xv[0]=xa[0]; xv[1]=xa[1]; xv[2]=xa[2]; xv[3]=xa[3];
    xv[4]=xb[0]; xv[5]=xb[1]; xv[6]=xb[2]; xv[7]=xb[3];
    if (t > 0) {
        f32x4 pa = *(const f32x4*)(x + (size_t)(row - 1) * D_DIM + base);
        f32x4 pb = *(const f32x4*)(x + (size_t)(row - 1) * D_DIM + base + 4);
        xp[0]=pa[0]; xp[1]=pa[1]; xp[2]=pa[2]; xp[3]=pa[3];
        xp[4]=pb[0]; xp[5]=pb[1]; xp[6]=pb[2]; xp[7]=pb[3];
    } else {
        #pragma unroll
        for (int j = 0; j < 8; j++) xp[j] = 0.f;
    }
    if (t == T_LEN - 1) {
        const int bb = row / T_LEN;
        *(f32x4*)(out2 + (size_t)bb * D_DIM + base)     = xa;
        *(f32x4*)(out2 + (size_t)bb * D_DIM + base + 4) = xb;
    }
    float mk[8], mr[8], xmk[8], xmr[8];
    f32x4 mka = *(const f32x4*)(muk + base), mkb = *(const f32x4*)(muk + base + 4);
    f32x4 mra = *(const f32x4*)(mur + base), mrb = *(const f32x4*)(mur + base + 4);
    mk[0]=mka[0]; mk[1]=mka[1]; mk[2]=mka[2]; mk[3]=mka[3];
    mk[4]=mkb[0]; mk[5]=mkb[1]; mk[6]=mkb[2]; mk[7]=mkb[3];
    mr[0]=mra[0]; mr[1]=mra[1]; mr[2]=mra[2]; mr[3]=mra[3];
    mr[4]=mrb[0]; mr[5]=mrb[1]; mr[6]=mrb[2]; mr[7]=mrb[3];
    #pragma unroll
    for (int j = 0; j < 8; j++) {
        const float dx = xp[j] - xv[j];
        xmk[j] = xv[j] + dx * mk[j];
        xmr[j] = xv[j] + dx * mr[j];
    }
    ln_quant8(xmk, gk, bk, qk, row, sk + row, red);
    ln_quant8(xmr, gr, br, qr, row, sr + row, red);
}

// -------- LN + act quant over H=8192 (k_act bf16, row-major in; packed int8 out) ----
__global__ void lnq_v(const unsigned short* __restrict__ kact,
                      const float* __restrict__ g, const float* __restrict__ b,
                      signed char* __restrict__ qv, float* __restrict__ sv) {
    __shared__ float red[16];
    const int row = blockIdx.x;
    const int base = threadIdx.x * 32;
    const unsigned short* kr = kact + (size_t)row * H_DIM + base;

    float v[32];
    float s = 0.f;
    #pragma unroll
    for (int c = 0; c < 4; c++) {
        ushort8 a = *(const ushort8*)(kr + c * 8);
        #pragma unroll
        for (int j = 0; j < 8; j++) { v[c * 8 + j] = bf2f(a[j]); s += v[c * 8 + j]; }
    }
    const float mean = block_sum(s, red) * (1.f / H_DIM);
    float s2 = 0.f;
    #pragma unroll
    for (int j = 0; j < 32; j++) { float d = v[j] - mean; s2 += d * d; }
    const float var  = block_sum(s2, red) * (1.f / H_DIM);
    const float rstd = 1.f / sqrtf(var + 1e-5f);
    float sa = 0.f;
    #pragma unroll
    for (int c = 0; c < 8; c++) {
        f32x4 ga = *(const f32x4*)(g + base + c * 4);
        f32x4 ba = *(const f32x4*)(b + base + c * 4);
        #pragma unroll
        for (int j = 0; j < 4; j++) {
            int k = c * 4 + j;
            v[k] = (v[k] - mean) * rstd * ga[j] + ba[j];
            sa += fabsf(v[k]);
        }
    }
    const float amean = block_sum(sa, red) * (1.f / H_DIM);
    const float scale = fmaxf(amean, 1e-8f) * 2.5f / 127.0f;
    union { signed char c[32]; i32x4v v4[2]; } pk;
    #pragma unroll
    for (int j = 0; j < 32; j++)
        pk.c[j] = (signed char)(int)rintf(fminf(fmaxf(v[j] / scale, -127.f), 127.f));
    // packed: 32 bytes = kslots tid*2, tid*2+1 of row-tile (row>>5)
    const size_t tb = ((size_t)(row >> 5) * (H_DIM / 16) + threadIdx.x * 2) * 512
                      + (row & 31) * 16;
    *(i32x4v*)(qv + tb)       = pk.v4[0];
    *(i32x4v*)(qv + tb + 512) = pk.v4[1];
    if (threadIdx.x == 0) sv[row] = scale;
}

// ======== gemmP: super-body pipelined i8 MFMA GEMM, packed-A-in-registers ========
// (r13-verified best structure: 602 us total, kact ~110 us @ MfmaUtil 26-27%)
// C[m,n] = sa[m]*sw * sum_k A[m,k]*B[n,k].  Tile 256x128, 512 thr (8 waves x 32 rows),
// super-body = 256 k-bytes (4 sub-tiles of 64), ONE barrier + ONE counted vmcnt per
// super-body.  B: 3-buffer LDS rotation (96 KB -> exactly 1 block/CU), verified BK=64
// swizzle f(r)=(r>>1)&3 per 8KB sub-buffer.  A: packed fragment layout -> each frag
// load is one fully-contiguous 1024B wave instr (compiler-tracked deps).
// vmcnt(12) = queue [B(t)4 < A(t)8 < B(t+1)4]: forces exactly B(t). Tail: vmcnt(8).
// 3-buffer rotation: stage of buf b at body t vs its previous read at body t-2 are
// separated by barrier(t-1) -> no WAR race with a single barrier per body.
// EP: 0 = relu(v)^2 -> bf16;  1 = sigmoid(v) -> bf16;  2 = out_f32 = bf16gate * v.
template <int EP>
__global__ __launch_bounds__(512, 2) void gemmP(
    const signed char* __restrict__ Ap, const signed char* __restrict__ B,
    int K, int Nn, int gn,
    const float* __restrict__ sa, const float* __restrict__ swp,
    const unsigned short* __restrict__ gate_bf, float* __restrict__ out_f,
    unsigned short* __restrict__ out_bf) {
    __shared__ signed char Bs[3 * 32768];
    const int tid = threadIdx.x;
    const int nwg = gridDim.x, q8 = nwg >> 3;     // nwg % 8 == 0 (host guarantees)
    const int swz = (blockIdx.x & 7) * q8 + (blockIdx.x >> 3);
    const int bm = swz / gn, bn = swz % gn;
    const int lane = tid & 63, wave = tid >> 6;
    const int lrow = lane & 31, lhalf = lane >> 5;
    const int KS = K >> 4;                         // kslots per row-tile
    const size_t rts = (size_t)(bm * 8 + wave) * KS;   // this wave's slot base
    const size_t brow0 = (size_t)bn * 128;
    const int NB = K >> 8;                         // super-bodies (8 or 32: even)

    i32x16v acc[4] = {};

    auto stageB = [&](int p, int t) {
        const int r = tid >> 2, sl = tid & 3;
        #pragma unroll
        for (int j = 0; j < 4; j++) {
            const signed char* g = B + (brow0 + r) * (size_t)K + (t * 256 + j * 64)
                                   + ((sl ^ ((r >> 1) & 3)) * 16);
            __builtin_amdgcn_global_load_lds(
                (const __attribute__((address_space(1))) void*)g,
                (__attribute__((address_space(3))) void*)(Bs + p * 32768 + j * 8192 + tid * 16),
                16, 0, 0);
        }
    };
    auto loadA = [&](i32x4v (&a)[4][2], int t) {
        #pragma unroll
        for (int s = 0; s < 4; s++)
            #pragma unroll
            for (int sl = 0; sl < 2; sl++)
                a[s][sl] = *(const i32x4v*)(
                    Ap + ((rts + (size_t)(t * 16 + s * 4 + sl * 2)) << 9) + lane * 16);
    };
    auto readB = [&](int p, int s, i32x4v (&b)[4][2]) {
        const signed char* basep = Bs + p * 32768 + s * 8192;
        #pragma unroll
        for (int sl = 0; sl < 2; sl++) {
            const int slot = sl * 2 + lhalf;
            #pragma unroll
            for (int tn = 0; tn < 4; tn++) {
                const int r = tn * 32 + lrow;
                b[tn][sl] = *(const i32x4v*)(basep + r * 64 + ((slot ^ ((r >> 1) & 3)) * 16));
            }
        }
    };

    auto bodyf = [&](int t, i32x4v (&aC)[4][2], i32x4v (&aN)[4][2]) {
        const int p = t % 3;
        const bool pf = (t + 1 < NB);
        if (pf) {
            stageB((t + 1) % 3, t + 1);
            asm volatile("s_waitcnt vmcnt(12)" ::: "memory");
        } else {
            asm volatile("s_waitcnt vmcnt(8)" ::: "memory");
        }
        __builtin_amdgcn_sched_barrier(0);
        __builtin_amdgcn_s_barrier();              // buf p data ready for all waves
        __builtin_amdgcn_sched_barrier(0);
        if (pf) loadA(aN, t + 1);                  // compiler-tracked register deps
        #pragma unroll
        for (int s = 0; s < 4; s++) {
            i32x4v b[4][2];
            readB(p, s, b);
            __builtin_amdgcn_s_setprio(1);
            #pragma unroll
            for (int sl = 0; sl < 2; sl++)
                #pragma unroll
                for (int tn = 0; tn < 4; tn++)
                    acc[tn] = __builtin_amdgcn_mfma_i32_32x32x32_i8(
                        aC[s][sl], b[tn][sl], acc[tn], 0, 0, 0);
            __builtin_amdgcn_s_setprio(0);
        }
    };

    i32x4v aE[4][2], aO[4][2];
    stageB(0, 0);
    loadA(aE, 0);
    for (int t = 0; t < NB; t += 2) {
        bodyf(t, aE, aO);
        bodyf(t + 1, aO, aE);
    }

    const float sw = *swp;
    #pragma unroll
    for (int tn = 0; tn < 4; tn++) {
        #pragma unroll
        for (int rg = 0; rg < 16; rg++) {
            const int rin  = (rg & 3) + 8 * (rg >> 2) + 4 * lhalf;
            const int grow = bm * 256 + wave * 32 + rin;
            const int gcol = bn * 128 + tn * 32 + lrow;
            const float v = (float)acc[tn][rg] * sa[grow] * sw;
            const size_t idx = (size_t)grow * Nn + gcol;
            if (EP == 0) {
                float rv = fmaxf(v, 0.f);
                out_bf[idx] = f2bf(rv * rv);
            } else if (EP == 1) {
                out_bf[idx] = f2bf(1.0f / (1.0f + expf(-v)));
            } else {
                out_f[idx] = bf2f(gate_bf[idx]) * v;
            }
        }
    }
}

extern "C" void kernel_launch(void* const* d_in, const int* in_sizes, int n_in,
                              void* d_out, int out_size, void* d_ws, size_t ws_size,
                              hipStream_t stream) {
    const float* x   = (const float*)d_in[0];
    const float* muk = (const float*)d_in[1];
    const float* mur = (const float*)d_in[2];
    const float* wk  = (const float*)d_in[3];
    const float* gk  = (const float*)d_in[4];
    const float* bk  = (const float*)d_in[5];
    const float* wr  = (const float*)d_in[6];
    const float* gr  = (const float*)d_in[7];
    const float* br  = (const float*)d_in[8];
    const float* wv  = (const float*)d_in[9];
    const float* gv  = (const float*)d_in[10];
    const float* bv  = (const float*)d_in[11];

    // ---- adaptive workspace layout (pure function of ws_size) ----
    char* wsb = (char*)d_ws;
    size_t off = 0;
    auto alloc = [&](size_t bytes) -> size_t {
        size_t p = off;
        off = (off + bytes + 255) & ~(size_t)255;
        return p;
    };
    const size_t o_wqk  = alloc((size_t)H_DIM * D_DIM);
    const size_t o_wqr  = alloc((size_t)D_DIM * D_DIM);
    const size_t o_wqv  = alloc((size_t)D_DIM * H_DIM);
    const size_t o_wsc  = alloc(64);
    const size_t o_part = alloc(3 * 1024 * sizeof(float));
    const size_t o_xqk  = alloc((size_t)BT * D_DIM);        // packed
    const size_t o_xqr  = alloc((size_t)BT * D_DIM);        // packed
    const size_t o_gate = alloc((size_t)BT * D_DIM * 2);    // bf16, row-major
    const size_t o_sk   = alloc((size_t)BT * 4);
    const size_t o_sr   = alloc((size_t)BT * 4);
    const size_t fixed  = off;

    int CH = BT;
    while (CH > 512 &&
           fixed + (size_t)CH * (H_DIM + 2 * H_DIM + 4) + 8192 > ws_size)
        CH >>= 1;
    const size_t o_xqv  = alloc((size_t)CH * H_DIM);        // packed
    const size_t o_kact = alloc((size_t)CH * H_DIM * 2);    // bf16, row-major
    const size_t o_sv   = alloc((size_t)CH * 4);

    signed char* wqk = (signed char*)(wsb + o_wqk);
    signed char* wqr = (signed char*)(wsb + o_wqr);
    signed char* wqv = (signed char*)(wsb + o_wqv);
    float* wsc  = (float*)(wsb + o_wsc);
    float* part = (float*)(wsb + o_part);
    signed char* xqk = (signed char*)(wsb + o_xqk);
    signed char* xqr = (signed char*)(wsb + o_xqr);
    unsigned short* gate = (unsigned short*)(wsb + o_gate);
    float* sk = (float*)(wsb + o_sk);
    float* sr = (float*)(wsb + o_sr);
    signed char* xqv = (signed char*)(wsb + o_xqv);
    unsigned short* kact = (unsigned short*)(wsb + o_kact);
    float* sv = (float*)(wsb + o_sv);

    float* outp = (float*)d_out;
    float* out2 = outp + (size_t)BT * D_DIM;

    // ---- fused weight prep ----
    wabs_all<<<3072, 256, 0, stream>>>(wk, wr, wv, part);
    wfinal_all<<<3, 256, 0, stream>>>(part, wsc);
    wquant_all<<<5120, 256, 0, stream>>>(wk, wr, wv, wqk, wqr, wqv, wsc);

    // ---- token shift + LN + act quant (packed), full BT ----
    act_prep<<<BT, 256, 0, stream>>>(x, muk, gk, bk, mur, gr, br,
                                     xqk, sk, xqr, sr, out2);

    // gate = sigmoid(bitlinear_r) -> bf16, full BT   [256x128, grid 512]
    gemmP<1><<<(BT / 256) * (D_DIM / 128), 512, 0, stream>>>(
        xqr, wqr, D_DIM, D_DIM, D_DIM / 128, sr, wsc + 1,
        (const unsigned short*)nullptr, (float*)nullptr, gate);

    // ---- row-chunked: kact -> lnq_v -> out ----
    for (int row0 = 0; row0 < BT; row0 += CH) {
        // kact = relu(bitlinear_k)^2 -> bf16   [256x128, grid (CH/256)*64]
        // packed-A offset for row0: (row0/32)*KS*512 == row0*D_DIM bytes
        gemmP<0><<<(CH / 256) * (H_DIM / 128), 512, 0, stream>>>(
            xqk + (size_t)row0 * D_DIM, wqk, D_DIM, H_DIM, H_DIM / 128,
            sk + row0, wsc + 0,
            (const unsigned short*)nullptr, (float*)nullptr, kact);

        lnq_v<<<CH, 256, 0, stream>>>(kact, gv, bv, xqv, sv);

        // out = bf16(gate) * bitlinear_v  (f32 -> d_out)   [256x128, grid (CH/256)*16]
        gemmP<2><<<(CH / 256) * (D_DIM / 128), 512, 0, stream>>>(
            xqv, wqv, H_DIM, D_DIM, D_DIM / 128, sv, wsc + 2,
            gate + (size_t)row0 * D_DIM, outp + (size_t)row0 * D_DIM,
            (unsigned short*)nullptr);
    }
}